// Round 13
// baseline (1378.596 us; speedup 1.0000x reference)
//
#include <hip/hip_runtime.h>
#include <hip/hip_bf16.h>

#define DD 128
#define NREL 8
#define LDHF 1036   // hbf row stride (f32): 1036%32=12 -> rows 12 banks apart, 2-way max (free, m136)
#define BC 16       // cols per block (one 16-row MFMA tile)

typedef float f32x4 __attribute__((ext_vector_type(4)));
typedef short short8 __attribute__((ext_vector_type(8)));

__device__ __forceinline__ float dis_f(float deg) {
    return deg == 0.0f ? 1.0f : rsqrtf(deg);
}

// pack 8 consecutive f32 -> 8 bf16 (short8) for MFMA A-fragment
__device__ __forceinline__ short8 pack8(const float* p) {
    union { short8 s; unsigned u[4]; } r;
    #pragma unroll
    for (int i = 0; i < 4; ++i) {
        __hip_bfloat162 b = __float22bfloat162_rn(make_float2(p[2 * i], p[2 * i + 1]));
        r.u[i] = *(unsigned*)&b;
    }
    return r.s;
}

// Fused prep: blocks [0,eb) do in-degree count; blocks [eb, eb+xblk) do x->bf16 convert.
__global__ __launch_bounds__(256) void prep_kernel(const int* __restrict__ ei,
                                                   int* __restrict__ cnt, int E, int eb,
                                                   const float* __restrict__ x,
                                                   __hip_bfloat16* __restrict__ xb, int total4) {
    if (blockIdx.x < (unsigned)eb) {
        int e = blockIdx.x * 256 + threadIdx.x;
        if (e < E) atomicAdd(&cnt[ei[E + e]], 1);
    } else {
        int i = (blockIdx.x - eb) * 256 + threadIdx.x;
        if (i >= total4) return;
        const float4 a = ((const float4*)x)[i];
        __hip_bfloat162 p0 = __float22bfloat162_rn(make_float2(a.x, a.y));
        __hip_bfloat162 p1 = __float22bfloat162_rn(make_float2(a.z, a.w));
        uint2 u;
        u.x = *(unsigned int*)&p0;
        u.y = *(unsigned int*)&p1;
        *(uint2*)&xb[(size_t)i * 4] = u;
    }
}

// 3-phase coalesced scan of ROUNDUP8(cnt) -> pstart[N+1] (+cursor copy, + pad records).
__global__ __launch_bounds__(256) void scanA_kernel(const int* __restrict__ cnt,
                                                    int* __restrict__ bsum, int N) {
    __shared__ int s[256];
    const int i = blockIdx.x * 256 + threadIdx.x;
    int v = (i < N) ? ((cnt[i] + 7) & ~7) : 0;
    s[threadIdx.x] = v;
    __syncthreads();
    for (int off = 1; off < 256; off <<= 1) {
        int add = (threadIdx.x >= off) ? s[threadIdx.x - off] : 0;
        __syncthreads();
        s[threadIdx.x] += add;
        __syncthreads();
    }
    if (threadIdx.x == 255) bsum[blockIdx.x] = s[255];
}

__global__ __launch_bounds__(256) void scanB_kernel(int* __restrict__ bsum,
                                                    int* __restrict__ pstart,
                                                    int nblk, int N) {
    __shared__ int s[256];
    const int t = threadIdx.x;
    int v = (t < nblk) ? bsum[t] : 0;
    s[t] = v;
    __syncthreads();
    for (int off = 1; off < 256; off <<= 1) {
        int add = (t >= off) ? s[t - off] : 0;
        __syncthreads();
        s[t] += add;
        __syncthreads();
    }
    if (t < nblk) bsum[t] = s[t] - v;      // exclusive block base
    if (t == 255) pstart[N] = s[255];      // grand total
}

// scanC also writes the per-col pad records (disjoint from bucket's slots -> order-free).
__global__ __launch_bounds__(256) void scanC_kernel(const int* __restrict__ cnt,
                                                    const int* __restrict__ bsum,
                                                    int* __restrict__ pstart,
                                                    int* __restrict__ cursor,
                                                    uint2* __restrict__ ebuf, int N) {
    __shared__ int s[256];
    const int i = blockIdx.x * 256 + threadIdx.x;
    const int cn = (i < N) ? cnt[i] : 0;
    const int v = (cn + 7) & ~7;
    s[threadIdx.x] = v;
    __syncthreads();
    for (int off = 1; off < 256; off <<= 1) {
        int add = (threadIdx.x >= off) ? s[threadIdx.x - off] : 0;
        __syncthreads();
        s[threadIdx.x] += add;
        __syncthreads();
    }
    if (i < N) {
        const int excl = s[threadIdx.x] - v + bsum[blockIdx.x];
        pstart[i] = excl;
        cursor[i] = excl;
        for (int j = cn; j < v; ++j) ebuf[excl + j] = make_uint2(0u, 0u);
    }
}

// Place edge records sorted by col at padded bases: rec = (et<<16 | row, coef).
__global__ __launch_bounds__(256) void bucket_kernel(const int* __restrict__ ei,
                                                     const int* __restrict__ et,
                                                     const float* __restrict__ ew,
                                                     const int* __restrict__ cnt,
                                                     int* __restrict__ cursor,
                                                     uint2* __restrict__ ebuf, int E) {
    int e = blockIdx.x * blockDim.x + threadIdx.x;
    if (e >= E) return;
    const int row = ei[e], col = ei[E + e];
    const float coef = dis_f((float)cnt[row]) * dis_f((float)cnt[col]) * ew[e];
    const int pos = atomicAdd(&cursor[col], 1);
    ebuf[pos] = make_uint2(((unsigned)et[e] << 16) | (unsigned)row, __float_as_uint(coef));
}

// BT[o][r*128+d] = bf16(W[r][d][o]) via LDS tile transpose (coalesced both sides).
__global__ __launch_bounds__(256) void wtrans_kernel(const float* __restrict__ W1,
                                                     const float* __restrict__ W2,
                                                     __hip_bfloat16* __restrict__ BT1,
                                                     __hip_bfloat16* __restrict__ BT2) {
    __shared__ __hip_bfloat16 tile[128][130];
    const int r = blockIdx.x & 7;
    const float* W = (blockIdx.x >> 3) ? W2 : W1;
    __hip_bfloat16* BT = (blockIdx.x >> 3) ? BT2 : BT1;
    const int o = threadIdx.x & 127;
    const int h = threadIdx.x >> 7;
    for (int d = h; d < DD; d += 2)
        tile[d][o] = __float2bfloat16(W[((size_t)r * DD + d) * DD + o]);
    __syncthreads();
    const int d = threadIdx.x & 127;
    for (int o2 = h; o2 < DD; o2 += 2)
        BT[(size_t)o2 * 1024 + r * DD + d] = tile[d][o2];
}

// Fused per-layer: scalar-load records -> PAIRED row loads (1 dwordx2 VMEM instruction
// serves 2 edges: lanes 0-31 = edge A's 128 dims, lanes 32-63 = edge B's) -> LDS fp32 h
// via ds_add_f32 atomics (race-safe when etA==etB; relation id is an address via cndmask,
// not a branch; no register accumulator -> no spill) -> MFMA with BT.
// Block = 16 cols, 8 waves; 2 cols per wave; one __syncthreads total.
template<int LAYER>
__global__ __launch_bounds__(512, 4) void fused_kernel(const __hip_bfloat16* __restrict__ srcb,
                                                       const uint2* __restrict__ ebuf,
                                                       const int* __restrict__ pstart, // [N+1]
                                                       const __hip_bfloat16* __restrict__ BT,
                                                       const float* __restrict__ bias,
                                                       const __hip_bfloat16* __restrict__ xbp,
                                                       __hip_bfloat16* __restrict__ z1b,
                                                       float* __restrict__ out, int N) {
    __shared__ float hbf[BC][LDHF];
    const int tid = threadIdx.x;
    const int w = tid >> 6, l = tid & 63;
    const int c0 = blockIdx.x * BC;
    const int j = l & 31;          // dim chunk: this lane covers d = 4j..4j+3 of its edge
    const int H = l >> 5;          // 0 -> even edge of pair, 1 -> odd edge

    // zero own rows (2w, 2w+1); wave-private rows -> no barrier needed before gather
    #pragma unroll
    for (int ii = l; ii < 1024; ii += 64) {
        hbf[2 * w][ii] = 0.f;
        hbf[2 * w + 1][ii] = 0.f;
    }

    #pragma unroll
    for (int q = 0; q < 2; ++q) {
        const int c = c0 + 2 * w + q;
        const int m = 2 * w + q;
        if (c < N) {
            const int beg = __builtin_amdgcn_readfirstlane(pstart[c]);
            const int end = __builtin_amdgcn_readfirstlane(pstart[c + 1]);
            // padded segment: (end-beg) % 8 == 0; 4 row-pairs per batch
            for (int e = beg; e < end; e += 8) {
                unsigned ms[8]; float cf[8];
                #pragma unroll
                for (int i = 0; i < 8; ++i) {
                    const uint2 rr = ebuf[e + i];          // uniform addr -> scalar load
                    ms[i] = (unsigned)__builtin_amdgcn_readfirstlane((int)rr.x);
                    cf[i] = __uint_as_float((unsigned)__builtin_amdgcn_readfirstlane((int)rr.y));
                }
                uint2 pv[4];
                #pragma unroll
                for (int p = 0; p < 4; ++p) {
                    const unsigned rowA = ms[2 * p] & 0xffffu;
                    const unsigned rowB = ms[2 * p + 1] & 0xffffu;
                    const unsigned row = H ? rowB : rowA;              // v_cndmask
                    pv[p] = *(const uint2*)&srcb[(size_t)row * DD + 4 * j]; // 1 VMEM, 2 edges
                }
                #pragma unroll
                for (int p = 0; p < 4; ++p) {
                    const int et = (int)((H ? ms[2 * p + 1] : ms[2 * p]) >> 16);
                    const float c_ = H ? cf[2 * p + 1] : cf[2 * p];
                    const float x0 = __uint_as_float(pv[p].x << 16);
                    const float x1 = __uint_as_float(pv[p].x & 0xffff0000u);
                    const float x2 = __uint_as_float(pv[p].y << 16);
                    const float x3 = __uint_as_float(pv[p].y & 0xffff0000u);
                    float* base = &hbf[m][et * DD + 4 * j];            // et -> address
                    atomicAdd(base + 0, c_ * x0);                      // ds_add_f32
                    atomicAdd(base + 1, c_ * x1);
                    atomicAdd(base + 2, c_ * x2);
                    atomicAdd(base + 3, c_ * x3);
                }
            }
        }
    }
    __syncthreads();

    // ---- MFMA: rows 0-15 x o-slice [w*16, w*16+16), K=1024; A packed f32->bf16 in-reg
    const int lk = (l >> 4) * 8;
    const int lr = l & 15;
    f32x4 acc0 = {0.f, 0.f, 0.f, 0.f};
    const __hip_bfloat16* bt = BT + (size_t)(w * 16 + lr) * 1024 + lk;
    const float* h0 = &hbf[lr][lk];
    #pragma unroll 8
    for (int k0 = 0; k0 < 1024; k0 += 32) {
        const short8 b  = *(const short8*)(bt + k0);
        const short8 a0 = pack8(h0 + k0);
        acc0 = __builtin_amdgcn_mfma_f32_16x16x32_bf16(a0, b, acc0, 0, 0, 0);
    }

    // ---- epilogue: D row=(l>>4)*4+q (graph col), col=l&15 (o)
    const int rbase = (l >> 4) * 4;
    const int o = w * 16 + lr;
    const float bv = bias[o];
    #pragma unroll
    for (int q = 0; q < 4; ++q) {
        const int c = c0 + rbase + q;
        if (c >= N) continue;
        const size_t idx = (size_t)c * DD + o;
        float v = acc0[q] + bv;
        if (LAYER == 1) {
            v = v >= 0.f ? v : 0.01f * v;   // leaky_relu
            z1b[idx] = __float2bfloat16(v);
        } else {
            const float z1v = __bfloat162float(z1b[idx]);
            const float xv2 = __bfloat162float(xbp[idx]);   // bf16 x: halves epilogue fetch
            out[idx] = (xv2 + z1v + v) * 0.25f;                  // z_star
            out[(size_t)N * DD + idx] = (z1v + v) * (1.f / 3.f); // z_sharp
        }
    }
}

extern "C" void kernel_launch(void* const* d_in, const int* in_sizes, int n_in,
                              void* d_out, int out_size, void* d_ws, size_t ws_size,
                              hipStream_t stream) {
    const float* x  = (const float*)d_in[0];
    const int*   ei = (const int*)d_in[1];
    const int*   et = (const int*)d_in[2];
    const float* ew = (const float*)d_in[3];
    const float* W1 = (const float*)d_in[4];
    const float* b1 = (const float*)d_in[5];
    const float* W2 = (const float*)d_in[6];
    const float* b2 = (const float*)d_in[7];

    const int N = in_sizes[0] / DD;
    const int E = in_sizes[3];
    float* out = (float*)d_out;

    // ws: cnt[N] | pstart[N+16] | cursor[N] | bsum[256] | BT1 | BT2 | ebuf[E+8N] | xb | z1b
    char* w = (char*)d_ws;
    int* cnt = (int*)w;                 w += (size_t)N * 4;
    int* pstart = (int*)w;              w += (size_t)(N + 16) * 4;
    int* cursor = (int*)w;              w += (size_t)N * 4;
    int* bsum = (int*)w;                w += 256 * 4;
    __hip_bfloat16* BT1 = (__hip_bfloat16*)w;  w += (size_t)DD * NREL * DD * 2;
    __hip_bfloat16* BT2 = (__hip_bfloat16*)w;  w += (size_t)DD * NREL * DD * 2;
    uint2* ebuf = (uint2*)w;            w += ((size_t)E + 8 * (size_t)N) * 8;
    __hip_bfloat16* xb = (__hip_bfloat16*)w;   w += (size_t)N * DD * 2;
    __hip_bfloat16* z1b = (__hip_bfloat16*)w;

    hipMemsetAsync(cnt, 0, (size_t)N * 4, stream);

    const int eb = (E + 255) / 256;
    const int t4 = N * DD / 4;
    const int xblk = (t4 + 255) / 256;
    const int nscb = (N + 255) / 256;   // <= 256 required (N <= 65536)

    prep_kernel<<<eb + xblk, 256, 0, stream>>>(ei, cnt, E, eb, x, xb, t4);
    wtrans_kernel<<<16, 256, 0, stream>>>(W1, W2, BT1, BT2);
    scanA_kernel<<<nscb, 256, 0, stream>>>(cnt, bsum, N);
    scanB_kernel<<<1, 256, 0, stream>>>(bsum, pstart, nscb, N);
    scanC_kernel<<<nscb, 256, 0, stream>>>(cnt, bsum, pstart, cursor, ebuf, N);
    bucket_kernel<<<eb, 256, 0, stream>>>(ei, et, ew, cnt, cursor, ebuf, E);

    const int nb = (N + BC - 1) / BC;
    fused_kernel<1><<<nb, 512, 0, stream>>>(xb,  ebuf, pstart, BT1, b1, xb, z1b, out, N);
    fused_kernel<2><<<nb, 512, 0, stream>>>(z1b, ebuf, pstart, BT2, b2, xb, z1b, out, N);
}

// Round 14
// 345.710 us; speedup vs baseline: 3.9877x; 3.9877x over previous
//
#include <hip/hip_runtime.h>
#include <hip/hip_bf16.h>

#define DD 128
#define NREL 8
#define LDHB 1032   // hb row stride (bf16): 2064B = 516 dwords = 4 mod 32 banks -> 2-way (free, m136)
#define BC 16       // cols per block (one 16-row MFMA tile)

typedef float f32x4 __attribute__((ext_vector_type(4)));
typedef short short8 __attribute__((ext_vector_type(8)));

__device__ __forceinline__ float dis_f(float deg) {
    return deg == 0.0f ? 1.0f : rsqrtf(deg);
}

// Fused prep: blocks [0,eb) do in-degree count; blocks [eb, eb+xblk) do x->bf16 convert.
__global__ __launch_bounds__(256) void prep_kernel(const int* __restrict__ ei,
                                                   int* __restrict__ cnt, int E, int eb,
                                                   const float* __restrict__ x,
                                                   __hip_bfloat16* __restrict__ xb, int total4) {
    if (blockIdx.x < (unsigned)eb) {
        int e = blockIdx.x * 256 + threadIdx.x;
        if (e < E) atomicAdd(&cnt[ei[E + e]], 1);
    } else {
        int i = (blockIdx.x - eb) * 256 + threadIdx.x;
        if (i >= total4) return;
        const float4 a = ((const float4*)x)[i];
        __hip_bfloat162 p0 = __float22bfloat162_rn(make_float2(a.x, a.y));
        __hip_bfloat162 p1 = __float22bfloat162_rn(make_float2(a.z, a.w));
        uint2 u;
        u.x = *(unsigned int*)&p0;
        u.y = *(unsigned int*)&p1;
        *(uint2*)&xb[(size_t)i * 4] = u;
    }
}

// 3-phase coalesced scan of ROUNDUP8(cnt) -> pstart[N+1] (+cursor copy, + pad records).
__global__ __launch_bounds__(256) void scanA_kernel(const int* __restrict__ cnt,
                                                    int* __restrict__ bsum, int N) {
    __shared__ int s[256];
    const int i = blockIdx.x * 256 + threadIdx.x;
    int v = (i < N) ? ((cnt[i] + 7) & ~7) : 0;
    s[threadIdx.x] = v;
    __syncthreads();
    for (int off = 1; off < 256; off <<= 1) {
        int add = (threadIdx.x >= off) ? s[threadIdx.x - off] : 0;
        __syncthreads();
        s[threadIdx.x] += add;
        __syncthreads();
    }
    if (threadIdx.x == 255) bsum[blockIdx.x] = s[255];
}

__global__ __launch_bounds__(256) void scanB_kernel(int* __restrict__ bsum,
                                                    int* __restrict__ pstart,
                                                    int nblk, int N) {
    __shared__ int s[256];
    const int t = threadIdx.x;
    int v = (t < nblk) ? bsum[t] : 0;
    s[t] = v;
    __syncthreads();
    for (int off = 1; off < 256; off <<= 1) {
        int add = (t >= off) ? s[t - off] : 0;
        __syncthreads();
        s[t] += add;
        __syncthreads();
    }
    if (t < nblk) bsum[t] = s[t] - v;      // exclusive block base
    if (t == 255) pstart[N] = s[255];      // grand total
}

// scanC also writes the per-col pad records (disjoint from bucket's slots -> order-free).
__global__ __launch_bounds__(256) void scanC_kernel(const int* __restrict__ cnt,
                                                    const int* __restrict__ bsum,
                                                    int* __restrict__ pstart,
                                                    int* __restrict__ cursor,
                                                    uint2* __restrict__ ebuf, int N) {
    __shared__ int s[256];
    const int i = blockIdx.x * 256 + threadIdx.x;
    const int cn = (i < N) ? cnt[i] : 0;
    const int v = (cn + 7) & ~7;
    s[threadIdx.x] = v;
    __syncthreads();
    for (int off = 1; off < 256; off <<= 1) {
        int add = (threadIdx.x >= off) ? s[threadIdx.x - off] : 0;
        __syncthreads();
        s[threadIdx.x] += add;
        __syncthreads();
    }
    if (i < N) {
        const int excl = s[threadIdx.x] - v + bsum[blockIdx.x];
        pstart[i] = excl;
        cursor[i] = excl;
        for (int j = cn; j < v; ++j) ebuf[excl + j] = make_uint2(0u, 0u);
    }
}

// Place edge records sorted by col at padded bases: rec = (et<<16 | row, coef).
__global__ __launch_bounds__(256) void bucket_kernel(const int* __restrict__ ei,
                                                     const int* __restrict__ et,
                                                     const float* __restrict__ ew,
                                                     const int* __restrict__ cnt,
                                                     int* __restrict__ cursor,
                                                     uint2* __restrict__ ebuf, int E) {
    int e = blockIdx.x * blockDim.x + threadIdx.x;
    if (e >= E) return;
    const int row = ei[e], col = ei[E + e];
    const float coef = dis_f((float)cnt[row]) * dis_f((float)cnt[col]) * ew[e];
    const int pos = atomicAdd(&cursor[col], 1);
    ebuf[pos] = make_uint2(((unsigned)et[e] << 16) | (unsigned)row, __float_as_uint(coef));
}

// BT[o][r*128+d] = bf16(W[r][d][o]) via LDS tile transpose (coalesced both sides).
__global__ __launch_bounds__(256) void wtrans_kernel(const float* __restrict__ W1,
                                                     const float* __restrict__ W2,
                                                     __hip_bfloat16* __restrict__ BT1,
                                                     __hip_bfloat16* __restrict__ BT2) {
    __shared__ __hip_bfloat16 tile[128][130];
    const int r = blockIdx.x & 7;
    const float* W = (blockIdx.x >> 3) ? W2 : W1;
    __hip_bfloat16* BT = (blockIdx.x >> 3) ? BT2 : BT1;
    const int o = threadIdx.x & 127;
    const int h = threadIdx.x >> 7;
    for (int d = h; d < DD; d += 2)
        tile[d][o] = __float2bfloat16(W[((size_t)r * DD + d) * DD + o]);
    __syncthreads();
    const int d = threadIdx.x & 127;
    for (int o2 = h; o2 < DD; o2 += 2)
        BT[(size_t)o2 * 1024 + r * DD + d] = tile[d][o2];
}

// Fused per-layer: scalar-load records (uint4-batched) -> 8-deep register gather
// (one col at a time, single acc bank: no spills) -> LDS h tile -> MFMA with BT.
// Block = 16 cols, 8 waves; 2 cols per wave; exactly one __syncthreads.
template<int LAYER>
__global__ __launch_bounds__(512, 8) void fused_kernel(const __hip_bfloat16* __restrict__ srcb,
                                                       const uint2* __restrict__ ebuf,
                                                       const int* __restrict__ pstart, // [N+1]
                                                       const __hip_bfloat16* __restrict__ BT,
                                                       const float* __restrict__ bias,
                                                       const __hip_bfloat16* __restrict__ xbp,
                                                       __hip_bfloat16* __restrict__ z1b,
                                                       float* __restrict__ out, int N) {
    __shared__ __hip_bfloat16 hb[BC][LDHB];
    const int tid = threadIdx.x;
    const int w = tid >> 6, l = tid & 63;
    const int c0 = blockIdx.x * BC;

    #pragma unroll
    for (int q = 0; q < 2; ++q) {
        const int c = c0 + 2 * w + q;
        float acc[16];
        #pragma unroll
        for (int i = 0; i < 16; ++i) acc[i] = 0.f;
        if (c < N) {
            const int beg = __builtin_amdgcn_readfirstlane(pstart[c]);
            const int end = __builtin_amdgcn_readfirstlane(pstart[c + 1]);
            // padded segment: beg/end multiples of 8 -> 16B-aligned uint4 record loads
            for (int e = beg; e < end; e += 8) {
                unsigned ms[8]; float cf[8]; unsigned vv[8];
                #pragma unroll
                for (int i = 0; i < 4; ++i) {              // 4x uint4 = 8 records
                    const uint4 rr = *(const uint4*)&ebuf[e + 2 * i];  // uniform addr
                    ms[2 * i]     = (unsigned)__builtin_amdgcn_readfirstlane((int)rr.x);
                    cf[2 * i]     = __uint_as_float((unsigned)__builtin_amdgcn_readfirstlane((int)rr.y));
                    ms[2 * i + 1] = (unsigned)__builtin_amdgcn_readfirstlane((int)rr.z);
                    cf[2 * i + 1] = __uint_as_float((unsigned)__builtin_amdgcn_readfirstlane((int)rr.w));
                }
                #pragma unroll
                for (int i = 0; i < 8; ++i)
                    vv[i] = *(const unsigned*)&srcb[(size_t)(ms[i] & 0xffffu) * DD + 2 * l];
                #pragma unroll
                for (int i = 0; i < 8; ++i) {
                    const float xl = __uint_as_float(vv[i] << 16);
                    const float xh = __uint_as_float(vv[i] & 0xffff0000u);
                    const float cf_ = cf[i];
                    switch (ms[i] >> 16) {                 // scalar branch, 2 accs touched
                        case 0: acc[0]  += cf_*xl; acc[1]  += cf_*xh; break;
                        case 1: acc[2]  += cf_*xl; acc[3]  += cf_*xh; break;
                        case 2: acc[4]  += cf_*xl; acc[5]  += cf_*xh; break;
                        case 3: acc[6]  += cf_*xl; acc[7]  += cf_*xh; break;
                        case 4: acc[8]  += cf_*xl; acc[9]  += cf_*xh; break;
                        case 5: acc[10] += cf_*xl; acc[11] += cf_*xh; break;
                        case 6: acc[12] += cf_*xl; acc[13] += cf_*xh; break;
                        default: acc[14] += cf_*xl; acc[15] += cf_*xh; break;
                    }
                }
            }
        }
        // h row -> LDS (bf16); frees acc for next col
        const int m = 2 * w + q;
        #pragma unroll
        for (int r = 0; r < NREL; ++r) {
            __hip_bfloat162 p = __float22bfloat162_rn(make_float2(acc[2 * r], acc[2 * r + 1]));
            *(unsigned int*)&hb[m][r * DD + 2 * l] = *(unsigned int*)&p;
        }
    }
    __syncthreads();

    // ---- MFMA: rows 0-15 x o-slice [w*16, w*16+16), K=1024
    const int lk = (l >> 4) * 8;
    const int lr = l & 15;
    f32x4 acc0 = {0.f, 0.f, 0.f, 0.f};
    const __hip_bfloat16* bt = BT + (size_t)(w * 16 + lr) * 1024 + lk;
    const __hip_bfloat16* h0 = &hb[lr][lk];
    #pragma unroll 8
    for (int k0 = 0; k0 < 1024; k0 += 32) {
        const short8 b  = *(const short8*)(bt + k0);
        const short8 a0 = *(const short8*)(h0 + k0);
        acc0 = __builtin_amdgcn_mfma_f32_16x16x32_bf16(a0, b, acc0, 0, 0, 0);
    }

    // ---- epilogue: D row=(l>>4)*4+q (graph col), col=l&15 (o)
    const int rbase = (l >> 4) * 4;
    const int o = w * 16 + lr;
    const float bv = bias[o];
    #pragma unroll
    for (int q = 0; q < 4; ++q) {
        const int c = c0 + rbase + q;
        if (c >= N) continue;
        const size_t idx = (size_t)c * DD + o;
        float v = acc0[q] + bv;
        if (LAYER == 1) {
            v = v >= 0.f ? v : 0.01f * v;   // leaky_relu
            z1b[idx] = __float2bfloat16(v);
        } else {
            const float z1v = __bfloat162float(z1b[idx]);
            const float xv2 = __bfloat162float(xbp[idx]);   // bf16 x: halves epilogue fetch
            out[idx] = (xv2 + z1v + v) * 0.25f;                  // z_star
            out[(size_t)N * DD + idx] = (z1v + v) * (1.f / 3.f); // z_sharp
        }
    }
}

extern "C" void kernel_launch(void* const* d_in, const int* in_sizes, int n_in,
                              void* d_out, int out_size, void* d_ws, size_t ws_size,
                              hipStream_t stream) {
    const float* x  = (const float*)d_in[0];
    const int*   ei = (const int*)d_in[1];
    const int*   et = (const int*)d_in[2];
    const float* ew = (const float*)d_in[3];
    const float* W1 = (const float*)d_in[4];
    const float* b1 = (const float*)d_in[5];
    const float* W2 = (const float*)d_in[6];
    const float* b2 = (const float*)d_in[7];

    const int N = in_sizes[0] / DD;
    const int E = in_sizes[3];
    float* out = (float*)d_out;

    // ws: cnt[N] | pstart[N+16] | cursor[N] | bsum[256] | BT1 | BT2 | ebuf[E+8N] | xb | z1b
    char* w = (char*)d_ws;
    int* cnt = (int*)w;                 w += (size_t)N * 4;
    int* pstart = (int*)w;              w += (size_t)(N + 16) * 4;
    int* cursor = (int*)w;              w += (size_t)N * 4;
    int* bsum = (int*)w;                w += 256 * 4;
    __hip_bfloat16* BT1 = (__hip_bfloat16*)w;  w += (size_t)DD * NREL * DD * 2;
    __hip_bfloat16* BT2 = (__hip_bfloat16*)w;  w += (size_t)DD * NREL * DD * 2;
    uint2* ebuf = (uint2*)w;            w += ((size_t)E + 8 * (size_t)N) * 8;
    __hip_bfloat16* xb = (__hip_bfloat16*)w;   w += (size_t)N * DD * 2;
    __hip_bfloat16* z1b = (__hip_bfloat16*)w;

    hipMemsetAsync(cnt, 0, (size_t)N * 4, stream);

    const int eb = (E + 255) / 256;
    const int t4 = N * DD / 4;
    const int xblk = (t4 + 255) / 256;
    const int nscb = (N + 255) / 256;   // <= 256 required (N <= 65536)

    prep_kernel<<<eb + xblk, 256, 0, stream>>>(ei, cnt, E, eb, x, xb, t4);
    wtrans_kernel<<<16, 256, 0, stream>>>(W1, W2, BT1, BT2);
    scanA_kernel<<<nscb, 256, 0, stream>>>(cnt, bsum, N);
    scanB_kernel<<<1, 256, 0, stream>>>(bsum, pstart, nscb, N);
    scanC_kernel<<<nscb, 256, 0, stream>>>(cnt, bsum, pstart, cursor, ebuf, N);
    bucket_kernel<<<eb, 256, 0, stream>>>(ei, et, ew, cnt, cursor, ebuf, E);

    const int nb = (N + BC - 1) / BC;
    fused_kernel<1><<<nb, 512, 0, stream>>>(xb,  ebuf, pstart, BT1, b1, xb, z1b, out, N);
    fused_kernel<2><<<nb, 512, 0, stream>>>(z1b, ebuf, pstart, BT2, b2, xb, z1b, out, N);
}